// Round 11
// baseline (530.567 us; speedup 1.0000x reference)
//
#include <hip/hip_runtime.h>
#include <cstdint>
#include <cstring>
#include <vector>
#include <numeric>
#include <algorithm>

// ============================================================================
// MetropolisHastingsPretrain: N=65536, D=48, H=256, 10 MH steps.
// Round-11 (= round-8 design, compile fix): GEMM on MFMA, bf16 4-product split.
//  * Round-10 compile error: local `const int b1` redefined the kernel
//    parameter `const float* b1` (illegal in the outermost block) -> renamed
//    fragment offsets to fo0/fo1. No functional change vs the round-8 design.
//  * fp32 pk_fma gives NO throughput gain on MI355X (SIMD-32 does 32 fp32
//    FMA/cyc total) -> fp32 GEMM floor 113 us of VALU issue. MFMA bf16 runs
//    on the separate matrix pipe and overlaps RNG/tanh VALU work.
//  * x = x_hi + x_lo, w = w_hi + w_lo (bf16 RNE splits); all 4 cross products
//    accumulated in fp32 MFMA -> error ~2^-18 rel; expected accept flips ~0.3
//    over 655k decisions, each bounded ~0.06 < 0.099 threshold.
//  * W pre-split & stored in B-fragment order in LDS (hi | lo, compacted;
//    k>=48 pad: B-read redirected, A-frags zero-masked).
//  * 16 samples/wave (full M=16 MFMA tile); 512 blocks x 512 thr;
//    X staged per-wave in LDS rows padded to 52 floats.
//  * C/D layout HW-verified (col=lane&15,row=(lane>>4)*4+reg); A/B assumed
//    canonical (m|n=lane&15, k=(lane>>4)*8+e).
// ============================================================================

typedef __attribute__((ext_vector_type(2))) float f32x2;
typedef __attribute__((ext_vector_type(4))) float f32x4;
typedef __attribute__((ext_vector_type(8))) short bf16x8;

static constexpr int kHalfN = 32768;
static constexpr int kSteps = 10;
static constexpr int kD = 48;     // NE*3
static constexpr int kH = 256;
static constexpr int kS = 16;     // samples per wave (one MFMA M-tile)
static constexpr int kWPB = 8;    // waves per block (512 threads)
static constexpr int kXPitch = 52;  // padded X row (floats) -> bank spread

struct StepKeys {
  uint32_t kn[2][kSteps][2];  // noise keys   [half][step][hi/lo]  (k1, k2)
  uint32_t ku[2][kSteps][2];  // uniform keys [half][step][hi/lo]  (k3, k4)
};

// ---------------- threefry2x32 (Random123 / JAX exact) ----------------------
__host__ __device__ __forceinline__ void tf2x32(uint32_t k0, uint32_t k1,
                                                uint32_t x0, uint32_t x1,
                                                uint32_t& y0, uint32_t& y1) {
  const uint32_t ks2 = k0 ^ k1 ^ 0x1BD11BDAu;
  x0 += k0; x1 += k1;
#define TFR(r) do { x0 += x1; x1 = (x1 << (r)) | (x1 >> (32 - (r))); x1 ^= x0; } while (0)
  TFR(13); TFR(15); TFR(26); TFR(6);
  x0 += k1;  x1 += ks2 + 1u;
  TFR(17); TFR(29); TFR(16); TFR(24);
  x0 += ks2; x1 += k0 + 2u;
  TFR(13); TFR(15); TFR(26); TFR(6);
  x0 += k0;  x1 += k1 + 3u;
  TFR(17); TFR(29); TFR(16); TFR(24);
  x0 += k1;  x1 += ks2 + 4u;
  TFR(13); TFR(15); TFR(26); TFR(6);
  x0 += ks2; x1 += k0 + 5u;
#undef TFR
  y0 = x0; y1 = x1;
}

__device__ __forceinline__ uint32_t tf_xor(uint32_t k0, uint32_t k1, uint32_t i) {
  uint32_t a, b;
  tf2x32(k0, k1, 0u, i, a, b);
  return a ^ b;
}

__device__ __forceinline__ float unit_from_bits(uint32_t bits) {
  return __uint_as_float((bits >> 9) | 0x3F800000u) - 1.0f;
}

// jax.random.normal: sqrt(2)*erfinv(max(lo, f*2+lo)); tail poly wave-skipped.
__device__ __forceinline__ float normal_from_bits(uint32_t bits) {
  const float f  = unit_from_bits(bits);
  const float lo = __uint_as_float(0xBF7FFFFFu);
  float u = __fadd_rn(__fmul_rn(f, 2.0f), lo);
  u = fmaxf(u, lo);
  const float uu = __fmul_rn(u, u);
  float w = -__logf(1.0f - uu);
  float wc = w - 2.5f;
  float p = 2.81022636e-08f;
  p = fmaf(p, wc, 3.43273939e-07f);
  p = fmaf(p, wc, -3.5233877e-06f);
  p = fmaf(p, wc, -4.39150654e-06f);
  p = fmaf(p, wc, 0.00021858087f);
  p = fmaf(p, wc, -0.00125372503f);
  p = fmaf(p, wc, -0.00417768164f);
  p = fmaf(p, wc, 0.246640727f);
  p = fmaf(p, wc, 1.50140941f);
  if (__any(w >= 5.0f)) {
    float wt = sqrtf(w) - 3.0f;
    float q = -0.000200214257f;
    q = fmaf(q, wt, 0.000100950558f);
    q = fmaf(q, wt, 0.00134934322f);
    q = fmaf(q, wt, -0.00367342844f);
    q = fmaf(q, wt, 0.00573950773f);
    q = fmaf(q, wt, -0.0076224613f);
    q = fmaf(q, wt, 0.00943887047f);
    q = fmaf(q, wt, 1.00167406f);
    q = fmaf(q, wt, 2.83297682f);
    p = (w < 5.0f) ? p : q;
  }
  return __fmul_rn(__uint_as_float(0x3FB504F3u), __fmul_rn(p, u));
}

__device__ __forceinline__ float readlane_f(float v, int l) {
  return __int_as_float(__builtin_amdgcn_readlane(__float_as_int(v), l));
}

// tanh(x) = 1 - 2/(1+e^{2x}); v_exp + v_rcp + 1 Newton.
__device__ __forceinline__ float fast_tanh(float x) {
  const float xc = fminf(x, 44.0f);
  const float t = __expf(xc + xc);
  const float a = t + 1.0f;
  float r = __builtin_amdgcn_rcpf(a);
  r = r * (2.0f - a * r);
  return fmaf(-2.0f, r, 1.0f);
}

__device__ __forceinline__ uint32_t bf16_rne_u(uint32_t u) {
  return (u + 0x7FFFu + ((u >> 16) & 1u)) >> 16;
}

union FragCast { uint32_t u[4]; bf16x8 v; };

// pack 2 f32 -> packed bf16x2 (word0=lo elem, word1=hi elem), RNE
__device__ __forceinline__ uint32_t cvtpk(float a, float b) {
  uint32_t r;
  asm("v_cvt_pk_bf16_f32 %0, %1, %2" : "=v"(r) : "v"(a), "v"(b));
  return r;
}

#define SWZ_ADD(X, P) \
  (X) += __int_as_float(__builtin_amdgcn_ds_swizzle(__float_as_int(X), (P)))

// One MLP eval for 16 samples via MFMA 16x16x32 bf16, 4-product split.
// sB: W fragments (hi at 0, lo at +12288 elems); xw: this wave's X rows.
// part[r] (after 16-lane butterfly) = log_amp of sample (lane>>4)*4+r.
__device__ __forceinline__ void evalMLP(const unsigned short* __restrict__ sB,
                                        const float* __restrict__ xw,
                                        int smp, int q, int fo0, int fo1,
                                        const float breg[16], const float wreg[16],
                                        f32x4& partOut) {
  const float* xrow = xw + smp * kXPitch;
  const f32x4 xa = *reinterpret_cast<const f32x4*>(xrow + q * 8);
  const f32x4 xb = *reinterpret_cast<const f32x4*>(xrow + q * 8 + 4);
  const int d1 = 32 + (q & 1) * 8;
  const f32x4 xc = *reinterpret_cast<const f32x4*>(xrow + d1);
  const f32x4 xd = *reinterpret_cast<const f32x4*>(xrow + d1 + 4);

  FragCast Ahi0, Alo0, Ahi1, Alo1;
#pragma unroll
  for (int j = 0; j < 2; ++j) {
    // kstep0 pairs from xa (j=0,1) and xb (j=0,1)
    {
      float a = xa[2 * j], b = xa[2 * j + 1];
      uint32_t h = cvtpk(a, b);
      float la = a - __uint_as_float(h << 16);
      float lb = b - __uint_as_float(h & 0xFFFF0000u);
      Ahi0.u[j] = h; Alo0.u[j] = cvtpk(la, lb);
    }
    {
      float a = xb[2 * j], b = xb[2 * j + 1];
      uint32_t h = cvtpk(a, b);
      float la = a - __uint_as_float(h << 16);
      float lb = b - __uint_as_float(h & 0xFFFF0000u);
      Ahi0.u[2 + j] = h; Alo0.u[2 + j] = cvtpk(la, lb);
    }
    {
      float a = xc[2 * j], b = xc[2 * j + 1];
      uint32_t h = cvtpk(a, b);
      float la = a - __uint_as_float(h << 16);
      float lb = b - __uint_as_float(h & 0xFFFF0000u);
      Ahi1.u[j] = h; Alo1.u[j] = cvtpk(la, lb);
    }
    {
      float a = xd[2 * j], b = xd[2 * j + 1];
      uint32_t h = cvtpk(a, b);
      float la = a - __uint_as_float(h << 16);
      float lb = b - __uint_as_float(h & 0xFFFF0000u);
      Ahi1.u[2 + j] = h; Alo1.u[2 + j] = cvtpk(la, lb);
    }
  }
  // kstep1 valid only for lanes q<2 (k = 32+q*8+e < 48); else zero A.
  const uint32_t msk = (q < 2) ? 0xFFFFFFFFu : 0u;
#pragma unroll
  for (int j = 0; j < 4; ++j) { Ahi1.u[j] &= msk; Alo1.u[j] &= msk; }

  f32x4 part = {0.f, 0.f, 0.f, 0.f};
#pragma unroll
  for (int t = 0; t < 16; ++t) {
    const bf16x8 bh0 = *reinterpret_cast<const bf16x8*>(sB + t * 768 + fo0);
    const bf16x8 bh1 = *reinterpret_cast<const bf16x8*>(sB + t * 768 + fo1);
    const bf16x8 bl0 = *reinterpret_cast<const bf16x8*>(sB + 12288 + t * 768 + fo0);
    const bf16x8 bl1 = *reinterpret_cast<const bf16x8*>(sB + 12288 + t * 768 + fo1);
    f32x4 c0 = {0.f, 0.f, 0.f, 0.f};
    f32x4 c1 = {0.f, 0.f, 0.f, 0.f};
    c0 = __builtin_amdgcn_mfma_f32_16x16x32_bf16(Ahi0.v, bh0, c0, 0, 0, 0);
    c1 = __builtin_amdgcn_mfma_f32_16x16x32_bf16(Alo0.v, bh0, c1, 0, 0, 0);
    c0 = __builtin_amdgcn_mfma_f32_16x16x32_bf16(Ahi1.v, bh1, c0, 0, 0, 0);
    c1 = __builtin_amdgcn_mfma_f32_16x16x32_bf16(Alo1.v, bh1, c1, 0, 0, 0);
    c0 = __builtin_amdgcn_mfma_f32_16x16x32_bf16(Ahi0.v, bl0, c0, 0, 0, 0);
    c1 = __builtin_amdgcn_mfma_f32_16x16x32_bf16(Alo0.v, bl0, c1, 0, 0, 0);
    c0 = __builtin_amdgcn_mfma_f32_16x16x32_bf16(Ahi1.v, bl1, c0, 0, 0, 0);
    c1 = __builtin_amdgcn_mfma_f32_16x16x32_bf16(Alo1.v, bl1, c1, 0, 0, 0);
#pragma unroll
    for (int r = 0; r < 4; ++r) {
      const float v = (c0[r] + c1[r]) + breg[t];
      part[r] = fmaf(fast_tanh(v), wreg[t], part[r]);
    }
  }
  // butterfly sum across the 16-lane column groups (xor 1,2,4,8)
#pragma unroll
  for (int r = 0; r < 4; ++r) SWZ_ADD(part[r], 0x041F);
#pragma unroll
  for (int r = 0; r < 4; ++r) SWZ_ADD(part[r], 0x081F);
#pragma unroll
  for (int r = 0; r < 4; ++r) SWZ_ADD(part[r], 0x101F);
#pragma unroll
  for (int r = 0; r < 4; ++r) SWZ_ADD(part[r], 0x201F);
  partOut = part;
}

// 512 blocks x 512 threads. Blocks [0,256): m-half, [256,512): h-half.
// Wave = 16 samples (one MFMA M-tile), full 10-step chain in registers.
__global__ __launch_bounds__(512, 2) void mh_chain_kernel(
    const float* __restrict__ curr,
    const float* __restrict__ W1, const float* __restrict__ b1, const float* __restrict__ w2,
    const float* __restrict__ Wh, const float* __restrict__ bh, const float* __restrict__ wh2,
    const uint32_t* __restrict__ iperm,
    float* __restrict__ out,
    StepKeys keys)
{
  __shared__ unsigned short sB[2 * 12288];              // 48 KB (hi | lo)
  __shared__ __align__(16) float sX[kWPB * kS * kXPitch];  // 26 KB
  const int bid  = (int)blockIdx.x;
  const int half = bid >= 256;
  const float* W    = half ? Wh  : W1;
  const float* bsrc = half ? bh  : b1;
  const float* wsrc = half ? wh2 : w2;

  // stage W -> bf16 hi/lo in B-fragment order:
  // elem (d,h): t=h>>4,c=h&15,s=d>>5,kl=d&31,qq=kl>>3,e=kl&7
  // idx = t*768 + s*512 + ((qq<<4)|c)*8 + e   (s=1 -> qq<2 -> compact)
  for (int i = (int)threadIdx.x; i < kD * kH; i += 512) {
    const int d = i >> 8, h = i & 255;
    const float w = W[i];
    const uint32_t hb = bf16_rne_u(__float_as_uint(w));
    const float lof = w - __uint_as_float(hb << 16);
    const uint32_t lb = bf16_rne_u(__float_as_uint(lof));
    const int t = h >> 4, c = h & 15, s = d >> 5, kl = d & 31;
    const int idx = t * 768 + s * 512 + (((kl >> 3) << 4) | c) * 8 + (kl & 7);
    sB[idx] = (unsigned short)hb;
    sB[12288 + idx] = (unsigned short)lb;
  }
  __syncthreads();

  const int wv   = (int)(threadIdx.x >> 6);
  const int lane = (int)(threadIdx.x & 63);
  const int smp  = lane & 15;       // MFMA A-row owner (sample)
  const int q    = lane >> 4;       // k-group
  float* xw = sX + wv * (kS * kXPitch);
  const int base    = ((bid & 255) << 7) | (wv << 4);  // first of 16 samples
  const int rowBase = half * kHalfN + base;

  // B-fragment element offsets (s1 reads for q>=2 redirected to s0: A is 0)
  const int fo0 = lane * 8;
  const int fo1 = (lane < 32) ? (512 + lane * 8) : (lane * 8);

  float breg[16], wreg[16];
#pragma unroll
  for (int t = 0; t < 16; ++t) {
    breg[t] = bsrc[t * 16 + smp];
    wreg[t] = wsrc[t * 16 + smp];
  }

  float sv[kS];
#pragma unroll
  for (int s = 0; s < kS; ++s)
    sv[s] = (lane < kD) ? curr[(rowBase + s) * kD + lane] : 0.f;
  if (lane < kD) {
#pragma unroll
    for (int s = 0; s < kS; ++s) xw[s * kXPitch + lane] = sv[s];
  }

  f32x4 part;
  evalMLP(sB, xw, smp, q, fo0, fo1, breg, wreg, part);
  float pc[kS];
#pragma unroll
  for (int s = 0; s < kS; ++s)
    pc[s] = __expf(__fmul_rn(2.0f, readlane_f(part[s & 3], (s >> 2) << 4)));

#pragma unroll 1
  for (int t = 0; t < kSteps; ++t) {
    const uint32_t kn0 = keys.kn[half][t][0], kn1 = keys.kn[half][t][1];
    const uint32_t ku0 = keys.ku[half][t][0], ku1 = keys.ku[half][t][1];

    float uvv, nw[kS];
    // pass 0: lanes<48 noise for sample 0; lanes 48..63 uniform bits s=0..15
    {
      const bool noiser = lane < kD;
      const uint32_t k0 = noiser ? kn0 : ku0;
      const uint32_t k1 = noiser ? kn1 : ku1;
      const uint32_t ctr = noiser ? (uint32_t)(base * kD + lane)
                                  : (uint32_t)(base + lane - 48);
      const uint32_t bits = tf_xor(k0, k1, ctr);
      const float nv = normal_from_bits(bits);
      uvv = unit_from_bits(bits);        // valid on lanes >= 48 (read later)
      nw[0] = __fadd_rn(sv[0], __fmul_rn(0.02f, nv));
    }
#pragma unroll
    for (int s = 1; s < kS; ++s) {
      const uint32_t bits = tf_xor(kn0, kn1, (uint32_t)((base + s) * kD + lane));
      nw[s] = __fadd_rn(sv[s], __fmul_rn(0.02f, normal_from_bits(bits)));
    }

    if (lane < kD) {
#pragma unroll
      for (int s = 0; s < kS; ++s) xw[s * kXPitch + lane] = nw[s];
    }
    f32x4 pn;
    evalMLP(sB, xw, smp, q, fo0, fo1, breg, wreg, pn);
#pragma unroll
    for (int s = 0; s < kS; ++s) {
      const float la = readlane_f(pn[s & 3], (s >> 2) << 4);
      const float e = __expf(__fmul_rn(2.0f, la));
      const float us = readlane_f(uvv, 48 + s);
      const bool ok = e > __fmul_rn(us, pc[s]);   // wave-uniform
      sv[s] = ok ? nw[s] : sv[s];
      pc[s] = ok ? e : pc[s];
    }
  }

  // scatter straight to permuted position: row g lands at j = iperm[g]
#pragma unroll
  for (int s = 0; s < kS; ++s) {
    const int dst = (int)iperm[rowBase + s];
    if (lane < kD) out[dst * kD + lane] = sv[s];
  }
}

// ---------------------------------------------------------------------------
// Load-time precompute: step keys + inverse permutation (fixed seeds only).
// ---------------------------------------------------------------------------
struct HostInit {
  StepKeys keys;
  uint32_t iperm[65536];
  HostInit() {
    const uint32_t k42_0 = 0u, k42_1 = 42u;  // jax.random.key(42)
    for (int t = 0; t < kSteps; ++t) {
      uint32_t sk0, sk1;
      tf2x32(k42_0, k42_1, 0u, (uint32_t)t, sk0, sk1);  // step_keys[t]
      uint32_t k[4][2];
      for (int j = 0; j < 4; ++j) tf2x32(sk0, sk1, 0u, (uint32_t)j, k[j][0], k[j][1]);
      keys.kn[0][t][0] = k[0][0]; keys.kn[0][t][1] = k[0][1];  // k1 -> sm noise
      keys.kn[1][t][0] = k[1][0]; keys.kn[1][t][1] = k[1][1];  // k2 -> sh noise
      keys.ku[0][t][0] = k[2][0]; keys.ku[0][t][1] = k[2][1];  // k3 -> mm uniform
      keys.ku[1][t][0] = k[3][0]; keys.ku[1][t][1] = k[3][1];  // k4 -> mh uniform
    }
    // permutation(key(7), 65536) = 2 rounds of stable sort by threefry bits
    const int n = 65536;
    uint32_t kc0 = 0u, kc1 = 7u;  // jax.random.key(7)
    std::vector<uint32_t> bits(n), val(n), idx(n), nv(n);
    std::iota(val.begin(), val.end(), 0u);
    for (int r = 0; r < 2; ++r) {
      uint32_t nk0, nk1, sub0, sub1;
      tf2x32(kc0, kc1, 0u, 0u, nk0, nk1);   // key  = split(key)[0]
      tf2x32(kc0, kc1, 0u, 1u, sub0, sub1); // subkey = split(key)[1]
      kc0 = nk0; kc1 = nk1;
      for (int i = 0; i < n; ++i) {
        uint32_t a, b;
        tf2x32(sub0, sub1, 0u, (uint32_t)i, a, b);
        bits[i] = a ^ b;
      }
      std::iota(idx.begin(), idx.end(), 0u);
      std::stable_sort(idx.begin(), idx.end(),
                       [&](uint32_t x, uint32_t y) { return bits[x] < bits[y]; });
      for (int i = 0; i < n; ++i) nv[i] = val[idx[i]];
      val.swap(nv);
    }
    for (int i = 0; i < n; ++i) iperm[val[i]] = (uint32_t)i;  // inverse
  }
};
static const HostInit g_init;

extern "C" void kernel_launch(void* const* d_in, const int* in_sizes, int n_in,
                              void* d_out, int out_size, void* d_ws, size_t ws_size,
                              hipStream_t stream) {
  (void)in_sizes; (void)n_in; (void)out_size; (void)ws_size;
  const float* curr = (const float*)d_in[0];
  const float* W1   = (const float*)d_in[1];
  const float* b1   = (const float*)d_in[2];
  const float* w2   = (const float*)d_in[3];
  const float* Wh   = (const float*)d_in[4];
  const float* bh   = (const float*)d_in[5];
  const float* wh2  = (const float*)d_in[6];
  float* out = (float*)d_out;

  (void)hipMemcpyAsync(d_ws, g_init.iperm, sizeof(g_init.iperm),
                       hipMemcpyHostToDevice, stream);

  mh_chain_kernel<<<dim3(512), dim3(512), 0, stream>>>(
      curr, W1, b1, w2, Wh, bh, wh2, (const uint32_t*)d_ws, out, g_init.keys);
}

// Round 12
// 527.364 us; speedup vs baseline: 1.0061x; 1.0061x over previous
//
#include <hip/hip_runtime.h>
#include <cstdint>
#include <cstring>
#include <vector>
#include <numeric>
#include <algorithm>

// ============================================================================
// MetropolisHastingsPretrain: N=65536, D=48, H=256, 10 MH steps.
// Round-12: kill the scratch spill found in round 11.
//  * Round-11 counters: FETCH 704MB / WRITE 153MB per dispatch (expected
//    ~25MB), HBM 24% peak, VALU 47%, Mfma 8.6% -> scratch-BW-bound.
//    Cause: FragCast UNIONS (.u[] writes / .v reads) defeat SROA -> A-frags
//    lowered to private memory, re-read 16x per eval from scratch.
//  * Fix: fragments built as scalar uint32_t SSA values; bf16x8 formed via
//    __builtin_bit_cast of an ext_vector. Bit-identical arithmetic.
//  * Everything else unchanged vs round 11 (absmax was 0.046875, in spec:
//    bf16 4-product split, ~2^-18 rel err, few accept flips, bound ~0.06).
// ============================================================================

typedef __attribute__((ext_vector_type(2))) float f32x2;
typedef __attribute__((ext_vector_type(4))) float f32x4;
typedef __attribute__((ext_vector_type(4))) unsigned int u32x4;
typedef __attribute__((ext_vector_type(8))) short bf16x8;

static constexpr int kHalfN = 32768;
static constexpr int kSteps = 10;
static constexpr int kD = 48;     // NE*3
static constexpr int kH = 256;
static constexpr int kS = 16;     // samples per wave (one MFMA M-tile)
static constexpr int kWPB = 8;    // waves per block (512 threads)
static constexpr int kXPitch = 52;  // padded X row (floats) -> bank spread

struct StepKeys {
  uint32_t kn[2][kSteps][2];  // noise keys   [half][step][hi/lo]  (k1, k2)
  uint32_t ku[2][kSteps][2];  // uniform keys [half][step][hi/lo]  (k3, k4)
};

// ---------------- threefry2x32 (Random123 / JAX exact) ----------------------
__host__ __device__ __forceinline__ void tf2x32(uint32_t k0, uint32_t k1,
                                                uint32_t x0, uint32_t x1,
                                                uint32_t& y0, uint32_t& y1) {
  const uint32_t ks2 = k0 ^ k1 ^ 0x1BD11BDAu;
  x0 += k0; x1 += k1;
#define TFR(r) do { x0 += x1; x1 = (x1 << (r)) | (x1 >> (32 - (r))); x1 ^= x0; } while (0)
  TFR(13); TFR(15); TFR(26); TFR(6);
  x0 += k1;  x1 += ks2 + 1u;
  TFR(17); TFR(29); TFR(16); TFR(24);
  x0 += ks2; x1 += k0 + 2u;
  TFR(13); TFR(15); TFR(26); TFR(6);
  x0 += k0;  x1 += k1 + 3u;
  TFR(17); TFR(29); TFR(16); TFR(24);
  x0 += k1;  x1 += ks2 + 4u;
  TFR(13); TFR(15); TFR(26); TFR(6);
  x0 += ks2; x1 += k0 + 5u;
#undef TFR
  y0 = x0; y1 = x1;
}

__device__ __forceinline__ uint32_t tf_xor(uint32_t k0, uint32_t k1, uint32_t i) {
  uint32_t a, b;
  tf2x32(k0, k1, 0u, i, a, b);
  return a ^ b;
}

__device__ __forceinline__ float unit_from_bits(uint32_t bits) {
  return __uint_as_float((bits >> 9) | 0x3F800000u) - 1.0f;
}

// jax.random.normal: sqrt(2)*erfinv(max(lo, f*2+lo)); tail poly wave-skipped.
__device__ __forceinline__ float normal_from_bits(uint32_t bits) {
  const float f  = unit_from_bits(bits);
  const float lo = __uint_as_float(0xBF7FFFFFu);
  float u = __fadd_rn(__fmul_rn(f, 2.0f), lo);
  u = fmaxf(u, lo);
  const float uu = __fmul_rn(u, u);
  float w = -__logf(1.0f - uu);
  float wc = w - 2.5f;
  float p = 2.81022636e-08f;
  p = fmaf(p, wc, 3.43273939e-07f);
  p = fmaf(p, wc, -3.5233877e-06f);
  p = fmaf(p, wc, -4.39150654e-06f);
  p = fmaf(p, wc, 0.00021858087f);
  p = fmaf(p, wc, -0.00125372503f);
  p = fmaf(p, wc, -0.00417768164f);
  p = fmaf(p, wc, 0.246640727f);
  p = fmaf(p, wc, 1.50140941f);
  if (__any(w >= 5.0f)) {
    float wt = sqrtf(w) - 3.0f;
    float q = -0.000200214257f;
    q = fmaf(q, wt, 0.000100950558f);
    q = fmaf(q, wt, 0.00134934322f);
    q = fmaf(q, wt, -0.00367342844f);
    q = fmaf(q, wt, 0.00573950773f);
    q = fmaf(q, wt, -0.0076224613f);
    q = fmaf(q, wt, 0.00943887047f);
    q = fmaf(q, wt, 1.00167406f);
    q = fmaf(q, wt, 2.83297682f);
    p = (w < 5.0f) ? p : q;
  }
  return __fmul_rn(__uint_as_float(0x3FB504F3u), __fmul_rn(p, u));
}

__device__ __forceinline__ float readlane_f(float v, int l) {
  return __int_as_float(__builtin_amdgcn_readlane(__float_as_int(v), l));
}

// tanh(x) = 1 - 2/(1+e^{2x}); v_exp + v_rcp + 1 Newton.
__device__ __forceinline__ float fast_tanh(float x) {
  const float xc = fminf(x, 44.0f);
  const float t = __expf(xc + xc);
  const float a = t + 1.0f;
  float r = __builtin_amdgcn_rcpf(a);
  r = r * (2.0f - a * r);
  return fmaf(-2.0f, r, 1.0f);
}

__device__ __forceinline__ uint32_t bf16_rne_u(uint32_t u) {
  return (u + 0x7FFFu + ((u >> 16) & 1u)) >> 16;
}

// pack 2 f32 -> packed bf16x2 (word0=lo elem, word1=hi elem), RNE
__device__ __forceinline__ uint32_t cvtpk(float a, float b) {
  uint32_t r;
  asm("v_cvt_pk_bf16_f32 %0, %1, %2" : "=v"(r) : "v"(a), "v"(b));
  return r;
}

// hi/lo bf16 split of a float pair -> two packed words (pure SSA, no memory)
__device__ __forceinline__ void split2(float a, float b,
                                       uint32_t& hi, uint32_t& lo) {
  hi = cvtpk(a, b);
  const float la = a - __uint_as_float(hi << 16);
  const float lb = b - __uint_as_float(hi & 0xFFFF0000u);
  lo = cvtpk(la, lb);
}

#define SWZ_ADD(X, P) \
  (X) += __int_as_float(__builtin_amdgcn_ds_swizzle(__float_as_int(X), (P)))

// One MLP eval for 16 samples via MFMA 16x16x32 bf16, 4-product split.
// sB: W fragments (hi at 0, lo at +12288 elems); xw: this wave's X rows.
// part[r] (after 16-lane butterfly) = log_amp of sample (lane>>4)*4+r.
__device__ __forceinline__ void evalMLP(const unsigned short* __restrict__ sB,
                                        const float* __restrict__ xw,
                                        int smp, int q, int fo0, int fo1,
                                        const float breg[16], const float wreg[16],
                                        f32x4& partOut) {
  const float* xrow = xw + smp * kXPitch;
  const f32x4 xa = *reinterpret_cast<const f32x4*>(xrow + q * 8);
  const f32x4 xb = *reinterpret_cast<const f32x4*>(xrow + q * 8 + 4);
  const int d1 = 32 + (q & 1) * 8;
  const f32x4 xc = *reinterpret_cast<const f32x4*>(xrow + d1);
  const f32x4 xd = *reinterpret_cast<const f32x4*>(xrow + d1 + 4);

  // A-fragments as scalar SSA words (no unions -> no scratch; round-11 bug)
  uint32_t h00, h01, h02, h03, l00, l01, l02, l03;
  uint32_t h10, h11, h12, h13, l10, l11, l12, l13;
  split2(xa[0], xa[1], h00, l00);
  split2(xa[2], xa[3], h01, l01);
  split2(xb[0], xb[1], h02, l02);
  split2(xb[2], xb[3], h03, l03);
  split2(xc[0], xc[1], h10, l10);
  split2(xc[2], xc[3], h11, l11);
  split2(xd[0], xd[1], h12, l12);
  split2(xd[2], xd[3], h13, l13);

  // kstep1 valid only for lanes q<2 (k = 32+q*8+e < 48); else zero A.
  const uint32_t msk = (q < 2) ? 0xFFFFFFFFu : 0u;
  const u32x4 vh0 = {h00, h01, h02, h03};
  const u32x4 vl0 = {l00, l01, l02, l03};
  const u32x4 vh1 = {h10 & msk, h11 & msk, h12 & msk, h13 & msk};
  const u32x4 vl1 = {l10 & msk, l11 & msk, l12 & msk, l13 & msk};
  const bf16x8 Ahi0 = __builtin_bit_cast(bf16x8, vh0);
  const bf16x8 Alo0 = __builtin_bit_cast(bf16x8, vl0);
  const bf16x8 Ahi1 = __builtin_bit_cast(bf16x8, vh1);
  const bf16x8 Alo1 = __builtin_bit_cast(bf16x8, vl1);

  f32x4 part = {0.f, 0.f, 0.f, 0.f};
#pragma unroll
  for (int t = 0; t < 16; ++t) {
    const bf16x8 bh0 = *reinterpret_cast<const bf16x8*>(sB + t * 768 + fo0);
    const bf16x8 bh1 = *reinterpret_cast<const bf16x8*>(sB + t * 768 + fo1);
    const bf16x8 bl0 = *reinterpret_cast<const bf16x8*>(sB + 12288 + t * 768 + fo0);
    const bf16x8 bl1 = *reinterpret_cast<const bf16x8*>(sB + 12288 + t * 768 + fo1);
    f32x4 c0 = {0.f, 0.f, 0.f, 0.f};
    f32x4 c1 = {0.f, 0.f, 0.f, 0.f};
    c0 = __builtin_amdgcn_mfma_f32_16x16x32_bf16(Ahi0, bh0, c0, 0, 0, 0);
    c1 = __builtin_amdgcn_mfma_f32_16x16x32_bf16(Alo0, bh0, c1, 0, 0, 0);
    c0 = __builtin_amdgcn_mfma_f32_16x16x32_bf16(Ahi1, bh1, c0, 0, 0, 0);
    c1 = __builtin_amdgcn_mfma_f32_16x16x32_bf16(Alo1, bh1, c1, 0, 0, 0);
    c0 = __builtin_amdgcn_mfma_f32_16x16x32_bf16(Ahi0, bl0, c0, 0, 0, 0);
    c1 = __builtin_amdgcn_mfma_f32_16x16x32_bf16(Alo0, bl0, c1, 0, 0, 0);
    c0 = __builtin_amdgcn_mfma_f32_16x16x32_bf16(Ahi1, bl1, c0, 0, 0, 0);
    c1 = __builtin_amdgcn_mfma_f32_16x16x32_bf16(Alo1, bl1, c1, 0, 0, 0);
#pragma unroll
    for (int r = 0; r < 4; ++r) {
      const float v = (c0[r] + c1[r]) + breg[t];
      part[r] = fmaf(fast_tanh(v), wreg[t], part[r]);
    }
  }
  // butterfly sum across the 16-lane column groups (xor 1,2,4,8)
#pragma unroll
  for (int r = 0; r < 4; ++r) SWZ_ADD(part[r], 0x041F);
#pragma unroll
  for (int r = 0; r < 4; ++r) SWZ_ADD(part[r], 0x081F);
#pragma unroll
  for (int r = 0; r < 4; ++r) SWZ_ADD(part[r], 0x101F);
#pragma unroll
  for (int r = 0; r < 4; ++r) SWZ_ADD(part[r], 0x201F);
  partOut = part;
}

// 512 blocks x 512 threads. Blocks [0,256): m-half, [256,512): h-half.
// Wave = 16 samples (one MFMA M-tile), full 10-step chain in registers.
__global__ __launch_bounds__(512, 2) void mh_chain_kernel(
    const float* __restrict__ curr,
    const float* __restrict__ W1, const float* __restrict__ b1, const float* __restrict__ w2,
    const float* __restrict__ Wh, const float* __restrict__ bh, const float* __restrict__ wh2,
    const uint32_t* __restrict__ iperm,
    float* __restrict__ out,
    StepKeys keys)
{
  __shared__ unsigned short sB[2 * 12288];              // 48 KB (hi | lo)
  __shared__ __align__(16) float sX[kWPB * kS * kXPitch];  // 26 KB
  const int bid  = (int)blockIdx.x;
  const int half = bid >= 256;
  const float* W    = half ? Wh  : W1;
  const float* bsrc = half ? bh  : b1;
  const float* wsrc = half ? wh2 : w2;

  // stage W -> bf16 hi/lo in B-fragment order:
  // elem (d,h): t=h>>4,c=h&15,s=d>>5,kl=d&31,qq=kl>>3,e=kl&7
  // idx = t*768 + s*512 + ((qq<<4)|c)*8 + e   (s=1 -> qq<2 -> compact)
  for (int i = (int)threadIdx.x; i < kD * kH; i += 512) {
    const int d = i >> 8, h = i & 255;
    const float w = W[i];
    const uint32_t hb = bf16_rne_u(__float_as_uint(w));
    const float lof = w - __uint_as_float(hb << 16);
    const uint32_t lb = bf16_rne_u(__float_as_uint(lof));
    const int t = h >> 4, c = h & 15, s = d >> 5, kl = d & 31;
    const int idx = t * 768 + s * 512 + (((kl >> 3) << 4) | c) * 8 + (kl & 7);
    sB[idx] = (unsigned short)hb;
    sB[12288 + idx] = (unsigned short)lb;
  }
  __syncthreads();

  const int wv   = (int)(threadIdx.x >> 6);
  const int lane = (int)(threadIdx.x & 63);
  const int smp  = lane & 15;       // MFMA A-row owner (sample)
  const int q    = lane >> 4;       // k-group
  float* xw = sX + wv * (kS * kXPitch);
  const int base    = ((bid & 255) << 7) | (wv << 4);  // first of 16 samples
  const int rowBase = half * kHalfN + base;

  // B-fragment element offsets (s1 reads for q>=2 redirected to s0: A is 0)
  const int fo0 = lane * 8;
  const int fo1 = (lane < 32) ? (512 + lane * 8) : (lane * 8);

  float breg[16], wreg[16];
#pragma unroll
  for (int t = 0; t < 16; ++t) {
    breg[t] = bsrc[t * 16 + smp];
    wreg[t] = wsrc[t * 16 + smp];
  }

  float sv[kS];
#pragma unroll
  for (int s = 0; s < kS; ++s)
    sv[s] = (lane < kD) ? curr[(rowBase + s) * kD + lane] : 0.f;
  if (lane < kD) {
#pragma unroll
    for (int s = 0; s < kS; ++s) xw[s * kXPitch + lane] = sv[s];
  }

  f32x4 part;
  evalMLP(sB, xw, smp, q, fo0, fo1, breg, wreg, part);
  float pc[kS];
#pragma unroll
  for (int s = 0; s < kS; ++s)
    pc[s] = __expf(__fmul_rn(2.0f, readlane_f(part[s & 3], (s >> 2) << 4)));

#pragma unroll 1
  for (int t = 0; t < kSteps; ++t) {
    const uint32_t kn0 = keys.kn[half][t][0], kn1 = keys.kn[half][t][1];
    const uint32_t ku0 = keys.ku[half][t][0], ku1 = keys.ku[half][t][1];

    float uvv, nw[kS];
    // pass 0: lanes<48 noise for sample 0; lanes 48..63 uniform bits s=0..15
    {
      const bool noiser = lane < kD;
      const uint32_t k0 = noiser ? kn0 : ku0;
      const uint32_t k1 = noiser ? kn1 : ku1;
      const uint32_t ctr = noiser ? (uint32_t)(base * kD + lane)
                                  : (uint32_t)(base + lane - 48);
      const uint32_t bits = tf_xor(k0, k1, ctr);
      const float nv = normal_from_bits(bits);
      uvv = unit_from_bits(bits);        // valid on lanes >= 48 (read later)
      nw[0] = __fadd_rn(sv[0], __fmul_rn(0.02f, nv));
    }
#pragma unroll
    for (int s = 1; s < kS; ++s) {
      const uint32_t bits = tf_xor(kn0, kn1, (uint32_t)((base + s) * kD + lane));
      nw[s] = __fadd_rn(sv[s], __fmul_rn(0.02f, normal_from_bits(bits)));
    }

    if (lane < kD) {
#pragma unroll
      for (int s = 0; s < kS; ++s) xw[s * kXPitch + lane] = nw[s];
    }
    f32x4 pn;
    evalMLP(sB, xw, smp, q, fo0, fo1, breg, wreg, pn);
#pragma unroll
    for (int s = 0; s < kS; ++s) {
      const float la = readlane_f(pn[s & 3], (s >> 2) << 4);
      const float e = __expf(__fmul_rn(2.0f, la));
      const float us = readlane_f(uvv, 48 + s);
      const bool ok = e > __fmul_rn(us, pc[s]);   // wave-uniform
      sv[s] = ok ? nw[s] : sv[s];
      pc[s] = ok ? e : pc[s];
    }
  }

  // scatter straight to permuted position: row g lands at j = iperm[g]
#pragma unroll
  for (int s = 0; s < kS; ++s) {
    const int dst = (int)iperm[rowBase + s];
    if (lane < kD) out[dst * kD + lane] = sv[s];
  }
}

// ---------------------------------------------------------------------------
// Load-time precompute: step keys + inverse permutation (fixed seeds only).
// ---------------------------------------------------------------------------
struct HostInit {
  StepKeys keys;
  uint32_t iperm[65536];
  HostInit() {
    const uint32_t k42_0 = 0u, k42_1 = 42u;  // jax.random.key(42)
    for (int t = 0; t < kSteps; ++t) {
      uint32_t sk0, sk1;
      tf2x32(k42_0, k42_1, 0u, (uint32_t)t, sk0, sk1);  // step_keys[t]
      uint32_t k[4][2];
      for (int j = 0; j < 4; ++j) tf2x32(sk0, sk1, 0u, (uint32_t)j, k[j][0], k[j][1]);
      keys.kn[0][t][0] = k[0][0]; keys.kn[0][t][1] = k[0][1];  // k1 -> sm noise
      keys.kn[1][t][0] = k[1][0]; keys.kn[1][t][1] = k[1][1];  // k2 -> sh noise
      keys.ku[0][t][0] = k[2][0]; keys.ku[0][t][1] = k[2][1];  // k3 -> mm uniform
      keys.ku[1][t][0] = k[3][0]; keys.ku[1][t][1] = k[3][1];  // k4 -> mh uniform
    }
    // permutation(key(7), 65536) = 2 rounds of stable sort by threefry bits
    const int n = 65536;
    uint32_t kc0 = 0u, kc1 = 7u;  // jax.random.key(7)
    std::vector<uint32_t> bits(n), val(n), idx(n), nv(n);
    std::iota(val.begin(), val.end(), 0u);
    for (int r = 0; r < 2; ++r) {
      uint32_t nk0, nk1, sub0, sub1;
      tf2x32(kc0, kc1, 0u, 0u, nk0, nk1);   // key  = split(key)[0]
      tf2x32(kc0, kc1, 0u, 1u, sub0, sub1); // subkey = split(key)[1]
      kc0 = nk0; kc1 = nk1;
      for (int i = 0; i < n; ++i) {
        uint32_t a, b;
        tf2x32(sub0, sub1, 0u, (uint32_t)i, a, b);
        bits[i] = a ^ b;
      }
      std::iota(idx.begin(), idx.end(), 0u);
      std::stable_sort(idx.begin(), idx.end(),
                       [&](uint32_t x, uint32_t y) { return bits[x] < bits[y]; });
      for (int i = 0; i < n; ++i) nv[i] = val[idx[i]];
      val.swap(nv);
    }
    for (int i = 0; i < n; ++i) iperm[val[i]] = (uint32_t)i;  // inverse
  }
};
static const HostInit g_init;

extern "C" void kernel_launch(void* const* d_in, const int* in_sizes, int n_in,
                              void* d_out, int out_size, void* d_ws, size_t ws_size,
                              hipStream_t stream) {
  (void)in_sizes; (void)n_in; (void)out_size; (void)ws_size;
  const float* curr = (const float*)d_in[0];
  const float* W1   = (const float*)d_in[1];
  const float* b1   = (const float*)d_in[2];
  const float* w2   = (const float*)d_in[3];
  const float* Wh   = (const float*)d_in[4];
  const float* bh   = (const float*)d_in[5];
  const float* wh2  = (const float*)d_in[6];
  float* out = (float*)d_out;

  (void)hipMemcpyAsync(d_ws, g_init.iperm, sizeof(g_init.iperm),
                       hipMemcpyHostToDevice, stream);

  mh_chain_kernel<<<dim3(512), dim3(512), 0, stream>>>(
      curr, W1, b1, w2, Wh, bh, wh2, (const uint32_t*)d_ws, out, g_init.keys);
}